// Round 4
// baseline (495.201 us; speedup 1.0000x reference)
//
#include <hip/hip_runtime.h>
#include <stdint.h>

// Problem constants (from reference): B=4, S=2048, D_IN=D_OUT=4096
constexpr int M = 4 * 2048;   // 8192 tokens
constexpr int K = 4096;       // D_IN
constexpr int N = 4096;       // D_OUT
constexpr float EPSf = 1e-5f;
constexpr float QMAX = 127.0f;

typedef __attribute__((ext_vector_type(8))) short bf16x8;    // 8 bf16 (4 VGPRs)
typedef __attribute__((ext_vector_type(16))) float f32x16;   // 32x32 MFMA C/D
typedef __attribute__((ext_vector_type(8))) unsigned short ushort8;

// bf16 round-to-nearest-even from f32 (no NaN inputs here)
__device__ __forceinline__ unsigned short f2bf(float f) {
  union { float f; uint32_t u; } c; c.f = f;
  uint32_t u = c.u;
  return (unsigned short)((u + 0x7fffu + ((u >> 16) & 1u)) >> 16);
}

__device__ __forceinline__ void async_copy16(const void* g, const void* l) {
  __builtin_amdgcn_global_load_lds(
      (const __attribute__((address_space(1))) unsigned int*)g,
      (__attribute__((address_space(3))) unsigned int*)l, 16, 0, 0);
}

// ---------------- Fused quant kernel: blocks [0,4096) = W rows, rest = X.
__global__ void __launch_bounds__(256) quant_fused_kernel(
    const float* __restrict__ x, unsigned short* __restrict__ xq,
    const float* __restrict__ w, unsigned short* __restrict__ wt,
    float* __restrict__ wscale) {
  const int tid = threadIdx.x;
  if (blockIdx.x < 4096) {
    // ---- W path: one block per row of 4096 ----
    const int row = blockIdx.x;
    const float* wr = w + (long)row * K;
    float4 v[4];
    float s = 0.f;
    #pragma unroll
    for (int p = 0; p < 4; p++) {
      v[p] = ((const float4*)wr)[tid + p * 256];
      s += fabsf(v[p].x) + fabsf(v[p].y) + fabsf(v[p].z) + fabsf(v[p].w);
    }
    #pragma unroll
    for (int d = 1; d < 64; d <<= 1) s += __shfl_xor(s, d);
    __shared__ float red[4];
    if ((tid & 63) == 0) red[tid >> 6] = s;
    __syncthreads();
    const float tot = red[0] + red[1] + red[2] + red[3];
    const float sc = fmaxf(tot / (float)K, EPSf);   // clip(mean|w|, EPS)
    if (tid == 0) wscale[row] = sc;
    unsigned short* wrow = wt + (long)row * K;
    #pragma unroll
    for (int p = 0; p < 4; p++) {
      ushort4 o;
      o.x = f2bf(fminf(fmaxf(rintf(v[p].x / sc), -1.f), 1.f));  // exact in bf16
      o.y = f2bf(fminf(fmaxf(rintf(v[p].y / sc), -1.f), 1.f));
      o.z = f2bf(fminf(fmaxf(rintf(v[p].z / sc), -1.f), 1.f));
      o.w = f2bf(fminf(fmaxf(rintf(v[p].w / sc), -1.f), 1.f));
      ((ushort4*)wrow)[tid + p * 256] = o;
    }
  } else {
    // ---- X path: 8 consecutive elems per thread (group64 = 8 lanes) ----
    const int t = ((int)blockIdx.x - 4096) * 256 + tid;   // 8-elem index
    const float4 v0 = ((const float4*)x)[2 * t];
    const float4 v1 = ((const float4*)x)[2 * t + 1];
    float m = fmaxf(
        fmaxf(fmaxf(fabsf(v0.x), fabsf(v0.y)), fmaxf(fabsf(v0.z), fabsf(v0.w))),
        fmaxf(fmaxf(fabsf(v1.x), fabsf(v1.y)), fmaxf(fabsf(v1.z), fabsf(v1.w))));
    #pragma unroll
    for (int d = 1; d < 8; d <<= 1) m = fmaxf(m, __shfl_xor(m, d));
    m = fmaxf(m, EPSf);                  // clip(absmax, EPS)
    const float scale = QMAX / m;        // exact div: ref's pre-round factor
    const float invs  = m * (1.0f / QMAX);
    const float q[8] = {v0.x, v0.y, v0.z, v0.w, v1.x, v1.y, v1.z, v1.w};
    ushort8 o;
    #pragma unroll
    for (int e = 0; e < 8; e++) {
      const float r = fminf(fmaxf(rintf(q[e] * scale), -QMAX), QMAX);
      o[e] = f2bf(r * invs);
    }
    ((ushort8*)xq)[t] = o;
  }
}

// ---------------- Kernel 3: 256x256-tile 8-phase GEMM, 32x32x16 MFMA variant
// C[M,N] = A[M,K] * Bt[N,K]^T, epilogue * wscale[n].
// 8 waves (2M x 4N), per-wave 128x64 output as 4(am)x2(ng) tiles of 32x32.
// BK=64, LDS 128 KiB dbuf. Staging / LDS layout / swizzle / vmcnt schedule
// IDENTICAL to the verified 16x16 version — only fragment reads, MFMA shape,
// and epilogue change. (R2 lesson: same-phase ds_read + lgkmcnt(0) coupling
// is load-bearing; do not decouple.)
//
// LDS layout (shorts), per buffer b (b*32768):
//   A half hh: [b*32768 + hh*8192], local row r (0..127) = grow mapping
//     grow = (r>>6)*128 + hh*64 + (r&63); 64 k per row (128 B = 8 chunks)
//   B half hh: [b*32768 + 16384 + hh*8192], col = (r>>5)*64 + hh*32 + (r&31)
//   phys 16B chunk = logical chunk ^ (local_row & 7)  [write via pre-swizzled
//   global source, read via XOR'd address — both-sides rule]
//
// 32x32x16 fragment reads (A/B 8 bf16 = 1 ds_read_b128 each):
//   A tile am (rows wm*128+am*32+[0,32)): LDS half hh=am>>1,
//     row = wm*64 + (am&1)*32 + (lane&31); k = kq*16 + (lane>>5)*8 + [0,8)
//   B group ng (cols wn*64+ng*32+[0,32)): LDS half hh=ng,
//     row = wn*32 + (lane&31); same k mapping.
//   C/D: col = lane&31, row = (reg&3) + 8*(reg>>2) + 4*(lane>>5).

#define BAR() do { asm volatile("" ::: "memory"); \
                   __builtin_amdgcn_s_barrier();  \
                   asm volatile("" ::: "memory"); } while (0)
#define LGKM0() asm volatile("s_waitcnt lgkmcnt(0)" ::: "memory")
#define LGKM8() asm volatile("s_waitcnt lgkmcnt(8)" ::: "memory")
#define VMCNT(n) asm volatile("s_waitcnt vmcnt(" #n ")" ::: "memory")

__global__ void __launch_bounds__(512, 2) gemm_bt_kernel(const short* __restrict__ A,
                                                         const short* __restrict__ Bt,
                                                         const float* __restrict__ wscale,
                                                         float* __restrict__ C) {
  __shared__ short smem[65536];   // 128 KiB: 2 buffers x (A 16K shorts | B 16K shorts)

  const int tid  = (int)threadIdx.x;
  const int lane = tid & 63;
  const int wv   = tid >> 6;
  const int wm = wv & 1, wn = wv >> 1;        // 2 M-waves x 4 N-waves
  const int hi  = lane >> 5;                  // k-group selector
  const int l31 = lane & 31;
  const int l7  = lane & 7;

  // T1: XCD-aware bijective swizzle (nwg=512, 512 % 8 == 0)
  const int f = (int)blockIdx.x;
  const int s = (f & 7) * 64 + (f >> 3);
  const int m0 = (s >> 4) * 256;              // 32 M-tiles
  const int n0 = (s & 15) * 256;              // 16 N-tiles

  const short* Ab = A  + (long)m0 * K;
  const short* Bb = Bt + (long)n0 * K;

  // Staging constants (unchanged): thread t, call c stages phys chunk (t&7)
  // of phys row c*64 + (t>>3); logical k-chunk = (t&7) ^ ((t>>3)&7).
  const int s_row8 = tid >> 3;                              // 0..63
  const int s_kc   = ((tid & 7) ^ (s_row8 & 7)) * 8;        // k elem offset (shorts)

  // ds_read swizzled k offsets (shorts) for kq = 0..3: logical chunk
  // kq*2 + hi, phys = ^ (row&7) = ^ l7 (rows differ from l31 by mult of 32).
  int ksw[4];
  #pragma unroll
  for (int kq = 0; kq < 4; ++kq)
    ksw[kq] = ((((kq * 2 + hi) * 16) ^ (l7 << 4)) >> 1);
  const int aroA = (wm * 64 + l31) * 64;      // A base row offset (shorts)
  const int broB = (wn * 32 + l31) * 64;      // B base row offset (shorts)

  f32x16 acc[4][2];
  #pragma unroll
  for (int i = 0; i < 4; i++)
    #pragma unroll
    for (int j = 0; j < 2; j++)
      #pragma unroll
      for (int r = 0; r < 16; r++) acc[i][j][r] = 0.f;

  bf16x8 af[2][4];        // current mi's two am-tiles (am&1, kq)
  bf16x8 bf_[2][4];       // both B groups persist     (ng, kq)

#define STAGE_A(buf, hh, kt) do {                                              \
    short* _d = smem + (buf) * 32768 + (hh) * 8192 + tid * 8;                  \
    const short* _g = Ab + (long)((hh) * 64 + s_row8) * K + (kt) * 64 + s_kc;  \
    async_copy16(_g, _d);                                                      \
    async_copy16(_g + (long)128 * K, _d + 4096);                               \
  } while (0)

#define STAGE_B(buf, hh, kt) do {                                              \
    short* _d = smem + (buf) * 32768 + 16384 + (hh) * 8192 + tid * 8;          \
    const int _r0 = (tid >> 8) * 64 + (hh) * 32 + (s_row8 & 31);               \
    const short* _g = Bb + (long)_r0 * K + (kt) * 64 + s_kc;                   \
    async_copy16(_g, _d);                                                      \
    async_copy16(_g + (long)128 * K, _d + 4096);                               \
  } while (0)

#define LOAD_A(buf, mi) do {                                                   \
    const short* _b = smem + (buf) * 32768 + (mi) * 8192 + aroA;               \
    _Pragma("unroll") for (int _a2 = 0; _a2 < 2; ++_a2)                        \
    _Pragma("unroll") for (int _kq = 0; _kq < 4; ++_kq)                        \
      af[_a2][_kq] = *(const bf16x8*)(_b + _a2 * 2048 + ksw[_kq]);             \
  } while (0)

#define LOAD_B(buf, ng) do {                                                   \
    const short* _b = smem + (buf) * 32768 + 16384 + (ng) * 8192 + broB;       \
    _Pragma("unroll") for (int _kq = 0; _kq < 4; ++_kq)                        \
      bf_[ng][_kq] = *(const bf16x8*)(_b + ksw[_kq]);                          \
  } while (0)

  // 8 MFMAs (2 am-tiles x 4 kq), kq-outer so adjacent instrs are independent.
#define MFMA_PHASE(mi, ng) do {                                                \
    BAR(); LGKM0();                                                            \
    __builtin_amdgcn_s_setprio(1);                                             \
    _Pragma("unroll") for (int _kq = 0; _kq < 4; ++_kq)                        \
    _Pragma("unroll") for (int _a2 = 0; _a2 < 2; ++_a2) {                      \
      acc[(mi)*2+_a2][ng] = __builtin_amdgcn_mfma_f32_32x32x16_bf16(           \
          af[_a2][_kq], bf_[ng][_kq], acc[(mi)*2+_a2][ng], 0, 0, 0);           \
    }                                                                          \
    __builtin_amdgcn_s_setprio(0);                                             \
  } while (0)

  // Prologue: stage half-tiles #0..6 (tile0 full + tile1 A0,B0,B1)
  STAGE_A(0, 0, 0); STAGE_B(0, 0, 0); STAGE_B(0, 1, 0); STAGE_A(0, 1, 0);
  VMCNT(4);
  STAGE_A(1, 0, 1); STAGE_B(1, 0, 1); STAGE_B(1, 1, 1);
  VMCNT(6);          // tile 0 fully resident; tile1 partials in flight
  BAR();

  for (int kt = 0; kt < 64; kt += 2) {
    const bool g2 = (kt + 2) < 64;
    const bool g3 = (kt + 3) < 64;

    // ======== tile kt (buf 0) ========
    // ph1: (mi0,ng0); 12 ds_reads -> lgkm throttle; stage tile kt+1 A1 -> buf1
    LOAD_A(0, 0); LOAD_B(0, 0);
    STAGE_A(1, 1, kt + 1);
    LGKM8();
    MFMA_PHASE(0, 0); BAR();
    // ph2: (mi0,ng1); stage tile kt+2 A0 -> buf0 (A0 read done in ph1)
    LOAD_B(0, 1);
    if (g2) STAGE_A(0, 0, kt + 2);
    MFMA_PHASE(0, 1); BAR();
    // ph3: (mi1,ng1); stage tile kt+2 B0 (bf_[0] cached in regs since ph1)
    LOAD_A(0, 1);
    if (g2) STAGE_B(0, 0, kt + 2);
    MFMA_PHASE(1, 1); BAR();
    // ph4: (mi1,ng0) from cached regs; stage tile kt+2 B1; tile boundary
    if (g2) STAGE_B(0, 1, kt + 2);
    MFMA_PHASE(1, 0);
    if (kt == 62) { VMCNT(0); } else { VMCNT(6); }   // next tile fully staged
    BAR();

    // ======== tile kt+1 (buf 1) ========
    // ph5: (mi0,ng0); 12 ds_reads -> throttle; stage tile kt+2 A1 -> buf0
    LOAD_A(1, 0); LOAD_B(1, 0);
    if (g2) STAGE_A(0, 1, kt + 2);
    LGKM8();
    MFMA_PHASE(0, 0); BAR();
    // ph6: (mi0,ng1); stage tile kt+3 A0 -> buf1
    LOAD_B(1, 1);
    if (g3) STAGE_A(1, 0, kt + 3);
    MFMA_PHASE(0, 1); BAR();
    // ph7: (mi1,ng1); stage tile kt+3 B0
    LOAD_A(1, 1);
    if (g3) STAGE_B(1, 0, kt + 3);
    MFMA_PHASE(1, 1); BAR();
    // ph8: (mi1,ng0); stage tile kt+3 B1; tile boundary
    if (g3) STAGE_B(1, 1, kt + 3);
    MFMA_PHASE(1, 0);
    if (g2) { VMCNT(6); BAR(); }    // else: last tile done, fall out
  }

  // Epilogue: 32x32 C/D mapping: col = l31, row = (reg&3)+8*(reg>>2)+4*hi.
  #pragma unroll
  for (int ng = 0; ng < 2; ++ng) {
    const int col = n0 + wn * 64 + ng * 32 + l31;
    const float sc = wscale[col];
    #pragma unroll
    for (int am = 0; am < 4; ++am) {
      const int rbase = m0 + wm * 128 + am * 32 + 4 * hi;
      #pragma unroll
      for (int reg = 0; reg < 16; ++reg) {
        const int row = rbase + (reg & 3) + 8 * (reg >> 2);
        C[(long)row * N + col] = acc[am][ng][reg] * sc;
      }
    }
  }
}

extern "C" void kernel_launch(void* const* d_in, const int* in_sizes, int n_in,
                              void* d_out, int out_size, void* d_ws, size_t ws_size,
                              hipStream_t stream) {
  const float* x   = (const float*)d_in[0];   // [4,2048,4096] fp32
  const float* wgt = (const float*)d_in[1];   // [4096,4096] fp32
  float* out = (float*)d_out;                 // [4,2048,4096] fp32

  // Workspace layout: A bf16 [M*K] | T bf16 [N*K] | wscale f32 [N]  (~96 MB)
  unsigned short* Aq = (unsigned short*)d_ws;
  unsigned short* Tq = Aq + (size_t)M * K;
  float* wscale = (float*)(Tq + (size_t)N * K);

  // One fused quant dispatch: blocks [0,4096) quantize W rows, blocks
  // [4096, 4096+16384) quantize X (8 elems/thread).
  quant_fused_kernel<<<4096 + (M * K / 8) / 256, 256, 0, stream>>>(
      x, Aq, wgt, Tq, wscale);

  gemm_bt_kernel<<<dim3(512), dim3(512), 0, stream>>>((const short*)Aq, (const short*)Tq,
                                                      wscale, out);
}

// Round 5
// 473.420 us; speedup vs baseline: 1.0460x; 1.0460x over previous
//
#include <hip/hip_runtime.h>
#include <stdint.h>

// Problem constants (from reference): B=4, S=2048, D_IN=D_OUT=4096
constexpr int M = 4 * 2048;   // 8192 tokens
constexpr int K = 4096;       // D_IN
constexpr int N = 4096;       // D_OUT
constexpr float EPSf = 1e-5f;
constexpr float QMAX = 127.0f;

typedef __attribute__((ext_vector_type(8))) short bf16x8;   // 8 bf16 (4 VGPRs)
typedef __attribute__((ext_vector_type(4))) float f32x4;    // MFMA C/D
typedef __attribute__((ext_vector_type(8))) unsigned short ushort8;

// bf16 round-to-nearest-even from f32 (no NaN inputs here)
__device__ __forceinline__ unsigned short f2bf(float f) {
  union { float f; uint32_t u; } c; c.f = f;
  uint32_t u = c.u;
  return (unsigned short)((u + 0x7fffu + ((u >> 16) & 1u)) >> 16);
}

__device__ __forceinline__ void async_copy16(const void* g, const void* l) {
  __builtin_amdgcn_global_load_lds(
      (const __attribute__((address_space(1))) unsigned int*)g,
      (__attribute__((address_space(3))) unsigned int*)l, 16, 0, 0);
}

// ---------------- Fused quant kernel: blocks [0,4096) = W rows, rest = X.
__global__ void __launch_bounds__(256) quant_fused_kernel(
    const float* __restrict__ x, unsigned short* __restrict__ xq,
    const float* __restrict__ w, unsigned short* __restrict__ wt,
    float* __restrict__ wscale) {
  const int tid = threadIdx.x;
  if (blockIdx.x < 4096) {
    // ---- W path: one block per row of 4096 ----
    const int row = blockIdx.x;
    const float* wr = w + (long)row * K;
    float4 v[4];
    float s = 0.f;
    #pragma unroll
    for (int p = 0; p < 4; p++) {
      v[p] = ((const float4*)wr)[tid + p * 256];
      s += fabsf(v[p].x) + fabsf(v[p].y) + fabsf(v[p].z) + fabsf(v[p].w);
    }
    #pragma unroll
    for (int d = 1; d < 64; d <<= 1) s += __shfl_xor(s, d);
    __shared__ float red[4];
    if ((tid & 63) == 0) red[tid >> 6] = s;
    __syncthreads();
    const float tot = red[0] + red[1] + red[2] + red[3];
    const float sc = fmaxf(tot / (float)K, EPSf);   // clip(mean|w|, EPS)
    if (tid == 0) wscale[row] = sc;
    unsigned short* wrow = wt + (long)row * K;
    #pragma unroll
    for (int p = 0; p < 4; p++) {
      ushort4 o;
      o.x = f2bf(fminf(fmaxf(rintf(v[p].x / sc), -1.f), 1.f));  // exact in bf16
      o.y = f2bf(fminf(fmaxf(rintf(v[p].y / sc), -1.f), 1.f));
      o.z = f2bf(fminf(fmaxf(rintf(v[p].z / sc), -1.f), 1.f));
      o.w = f2bf(fminf(fmaxf(rintf(v[p].w / sc), -1.f), 1.f));
      ((ushort4*)wrow)[tid + p * 256] = o;
    }
  } else {
    // ---- X path: 8 consecutive elems per thread (group64 = 8 lanes) ----
    const int t = ((int)blockIdx.x - 4096) * 256 + tid;   // 8-elem index
    const float4 v0 = ((const float4*)x)[2 * t];
    const float4 v1 = ((const float4*)x)[2 * t + 1];
    float m = fmaxf(
        fmaxf(fmaxf(fabsf(v0.x), fabsf(v0.y)), fmaxf(fabsf(v0.z), fabsf(v0.w))),
        fmaxf(fmaxf(fabsf(v1.x), fabsf(v1.y)), fmaxf(fabsf(v1.z), fabsf(v1.w))));
    #pragma unroll
    for (int d = 1; d < 8; d <<= 1) m = fmaxf(m, __shfl_xor(m, d));
    m = fmaxf(m, EPSf);                  // clip(absmax, EPS)
    const float scale = QMAX / m;        // exact div: ref's pre-round factor
    const float invs  = m * (1.0f / QMAX);
    const float q[8] = {v0.x, v0.y, v0.z, v0.w, v1.x, v1.y, v1.z, v1.w};
    ushort8 o;
    #pragma unroll
    for (int e = 0; e < 8; e++) {
      const float r = fminf(fmaxf(rintf(q[e] * scale), -QMAX), QMAX);
      o[e] = f2bf(r * invs);
    }
    ((ushort8*)xq)[t] = o;
  }
}

// ---------------- Kernel 3: 256x256-tile 8-phase GEMM, SINGLE-buffer LDS
// C[M,N] = A[M,K] * Bt[N,K]^T, epilogue * wscale[n].
// 8 waves (2M x 4N), per-wave 128x64 output, BK=64. 16x16x32 MFMA (r3-verified
// fragment paths; r4's 32x32 swap caused 2.5e7 bank conflicts -> reverted).
//
// vs r3: LDS double-buffer dropped -> 64 KiB -> 2 blocks/CU. At 128 KiB only
// 1 block/CU was resident (Occupancy 22%), so barrier/vmcnt rendezvous had
// nothing to overlap with. WAR safety without dbuf comes from the schedule:
// half H of tile t is last ds_read in a known phase, and MFMA_PHASE's LGKM0
// completes each wave's reads before its closing barrier, so staging H(t+1)
// in the NEXT phase is race-free (write lands after issue, issue after bar).
//
// Per-wave stage issue: ph2={A0,B0}(4 loads), ph3={B1}(2), ph4={A1}(2).
// Gates (each vmcnt precedes a barrier -> collective):
//   ph4-end vmcnt(4): A0,B0 of next tile landed (for ph1 reads)
//   ph1-end vmcnt(2): B1 landed (for ph2 reads)
//   ph2-end vmcnt(4) [vmcnt(0) at tail]: A1 landed (for ph3 reads)
// Every gated load is >=3 phases (~1800 cyc) old >= ~900 cyc HBM latency.
//
// LDS layout (shorts): A half hh at [hh*8192], B half hh at [16384 + hh*8192].
// Swizzle: phys 16B chunk = logical chunk ^ (row&7); applied via pre-swizzled
// global source (linear gload_lds dest) + XOR'd ds_read address (rule #21).
// (R2 lesson: same-phase ds_read + lgkmcnt(0) coupling is load-bearing.)

#define BAR() do { asm volatile("" ::: "memory"); \
                   __builtin_amdgcn_s_barrier();  \
                   asm volatile("" ::: "memory"); } while (0)
#define LGKM0() asm volatile("s_waitcnt lgkmcnt(0)" ::: "memory")
#define VMCNT(n) asm volatile("s_waitcnt vmcnt(" #n ")" ::: "memory")

__global__ void __launch_bounds__(512, 2) gemm_bt_kernel(const short* __restrict__ A,
                                                         const short* __restrict__ Bt,
                                                         const float* __restrict__ wscale,
                                                         float* __restrict__ C) {
  __shared__ short smem[32768];   // 64 KiB: A 16K shorts | B 16K shorts

  const int tid  = (int)threadIdx.x;
  const int lane = tid & 63;
  const int wv   = tid >> 6;
  const int wm = wv & 1, wn = wv >> 1;        // 2 M-waves x 4 N-waves
  const int quad = lane >> 4, r16 = lane & 15;

  // T1: XCD-aware bijective swizzle (nwg=512, 512 % 8 == 0)
  const int f = (int)blockIdx.x;
  const int s = (f & 7) * 64 + (f >> 3);
  const int m0 = (s >> 4) * 256;              // 32 M-tiles
  const int n0 = (s & 15) * 256;              // 16 N-tiles

  const short* Ab = A  + (long)m0 * K;
  const short* Bb = Bt + (long)n0 * K;

  // Staging constants: thread t, call c stages phys chunk (t&7) of phys row
  // c*64 + (t>>3); logical k-chunk = (t&7) ^ ((t>>3)&7)  (inverse swizzle).
  const int s_row8 = tid >> 3;                              // 0..63
  const int s_kc   = ((tid & 7) ^ (s_row8 & 7)) * 8;        // k elem offset (shorts)

  // ds_read constants: logical chunk kh*4+quad, phys = ^(r16&7); shorts offsets
  const int ksw0 = (((quad * 16)      ) ^ ((r16 & 7) << 4)) >> 1;  // kh=0
  const int ksw1 = (((quad * 16) + 64 ) ^ ((r16 & 7) << 4)) >> 1;  // kh=1
  const int aro  = (wm * 64 + r16) * 64;      // A slot row offset (shorts)
  const int bro  = (wn * 32 + r16) * 64;      // B slot row offset (shorts)

  f32x4 acc[8][4];
  #pragma unroll
  for (int i = 0; i < 8; i++)
    #pragma unroll
    for (int j = 0; j < 4; j++) acc[i][j] = (f32x4){0.f, 0.f, 0.f, 0.f};

  bf16x8 af[4][2];        // current A half fragments (mt, kh)
  bf16x8 bf_[2][2][2];    // both B halves persist     (nj, nt, kh)

#define STAGE_A(hh, kt) do {                                                   \
    short* _d = smem + (hh) * 8192 + tid * 8;                                  \
    const short* _g = Ab + (long)((hh) * 64 + s_row8) * K + (kt) * 64 + s_kc;  \
    async_copy16(_g, _d);                                                      \
    async_copy16(_g + (long)128 * K, _d + 4096);                               \
  } while (0)

#define STAGE_B(hh, kt) do {                                                   \
    short* _d = smem + 16384 + (hh) * 8192 + tid * 8;                          \
    const int _r0 = (tid >> 8) * 64 + (hh) * 32 + (s_row8 & 31);               \
    const short* _g = Bb + (long)_r0 * K + (kt) * 64 + s_kc;                   \
    async_copy16(_g, _d);                                                      \
    async_copy16(_g + (long)128 * K, _d + 4096);                               \
  } while (0)

#define LOAD_A(mi) do {                                                        \
    const short* _b = smem + (mi) * 8192 + aro;                                \
    _Pragma("unroll") for (int _mt = 0; _mt < 4; ++_mt) {                      \
      af[_mt][0] = *(const bf16x8*)(_b + _mt * 1024 + ksw0);                   \
      af[_mt][1] = *(const bf16x8*)(_b + _mt * 1024 + ksw1);                   \
    }                                                                          \
  } while (0)

#define LOAD_B(nj) do {                                                        \
    const short* _b = smem + 16384 + (nj) * 8192 + bro;                        \
    _Pragma("unroll") for (int _nt = 0; _nt < 2; ++_nt) {                      \
      bf_[nj][_nt][0] = *(const bf16x8*)(_b + _nt * 1024 + ksw0);              \
      bf_[nj][_nt][1] = *(const bf16x8*)(_b + _nt * 1024 + ksw1);              \
    }                                                                          \
  } while (0)

#define MFMA_PHASE(mi, nj) do {                                                \
    BAR(); LGKM0();                                                            \
    __builtin_amdgcn_s_setprio(1);                                             \
    _Pragma("unroll") for (int _mt = 0; _mt < 4; ++_mt)                        \
    _Pragma("unroll") for (int _nt = 0; _nt < 2; ++_nt) {                      \
      acc[(mi)*4+_mt][(nj)*2+_nt] = __builtin_amdgcn_mfma_f32_16x16x32_bf16(   \
          af[_mt][0], bf_[nj][_nt][0], acc[(mi)*4+_mt][(nj)*2+_nt], 0, 0, 0);  \
      acc[(mi)*4+_mt][(nj)*2+_nt] = __builtin_amdgcn_mfma_f32_16x16x32_bf16(   \
          af[_mt][1], bf_[nj][_nt][1], acc[(mi)*4+_mt][(nj)*2+_nt], 0, 0, 0);  \
    }                                                                          \
    __builtin_amdgcn_s_setprio(0);                                             \
  } while (0)

  // Prologue: stage tile 0 in steady-state order {A0,B0,B1,A1}; gate A0,B0.
  STAGE_A(0, 0); STAGE_B(0, 0); STAGE_B(1, 0); STAGE_A(1, 0);
  VMCNT(4);
  BAR();

  for (int kt = 0; kt < 64; ++kt) {
    const bool g = kt < 63;
    // ph1: (mi0,nj0); reads A0,B0 (staged >=3 phases ago; gated at ph4-end)
    LOAD_A(0); LOAD_B(0);
    MFMA_PHASE(0, 0);
    VMCNT(2);                      // gate B1(kt) for ph2
    BAR();
    // ph2: (mi0,nj1); reads B1; stage A0,B0 of kt+1 (A0/B0 fully read in ph1)
    LOAD_B(1);
    if (g) { STAGE_A(0, kt + 1); STAGE_B(0, kt + 1); }
    MFMA_PHASE(0, 1);
    if (g) { VMCNT(4); } else { VMCNT(0); }   // gate A1(kt) for ph3
    BAR();
    // ph3: (mi1,nj1); reads A1; stage B1 of kt+1 (B1 fully read in ph2)
    LOAD_A(1);
    if (g) STAGE_B(1, kt + 1);
    MFMA_PHASE(1, 1);
    BAR();
    // ph4: (mi1,nj0) from cached regs; stage A1 of kt+1 (A1 fully read in ph3)
    if (g) STAGE_A(1, kt + 1);
    MFMA_PHASE(1, 0);
    if (g) {
      VMCNT(4);                    // gate A0,B0 of kt+1 for next ph1
      BAR();
    }
  }

  // Epilogue: D[row = quad*4+r][col = r16] per 16x16 frag; scale by wscale[col]
  #pragma unroll
  for (int an = 0; an < 4; ++an) {
    const int col = n0 + wn * 64 + (an >> 1) * 32 + (an & 1) * 16 + r16;
    const float sc = wscale[col];
    #pragma unroll
    for (int am = 0; am < 8; ++am) {
      const int rb = m0 + wm * 128 + (am >> 2) * 64 + (am & 3) * 16 + quad * 4;
      #pragma unroll
      for (int r = 0; r < 4; ++r)
        C[(long)(rb + r) * N + col] = acc[am][an][r] * sc;
    }
  }
}

extern "C" void kernel_launch(void* const* d_in, const int* in_sizes, int n_in,
                              void* d_out, int out_size, void* d_ws, size_t ws_size,
                              hipStream_t stream) {
  const float* x   = (const float*)d_in[0];   // [4,2048,4096] fp32
  const float* wgt = (const float*)d_in[1];   // [4096,4096] fp32
  float* out = (float*)d_out;                 // [4,2048,4096] fp32

  // Workspace layout: A bf16 [M*K] | T bf16 [N*K] | wscale f32 [N]  (~96 MB)
  unsigned short* Aq = (unsigned short*)d_ws;
  unsigned short* Tq = Aq + (size_t)M * K;
  float* wscale = (float*)(Tq + (size_t)N * K);

  // One fused quant dispatch: blocks [0,4096) quantize W rows, blocks
  // [4096, 4096+16384) quantize X (8 elems/thread).
  quant_fused_kernel<<<4096 + (M * K / 8) / 256, 256, 0, stream>>>(
      x, Aq, wgt, Tq, wscale);

  gemm_bt_kernel<<<dim3(512), dim3(512), 0, stream>>>((const short*)Aq, (const short*)Tq,
                                                      wscale, out);
}